// Round 1
// baseline (5172.936 us; speedup 1.0000x reference)
//
#include <hip/hip_runtime.h>
#include <hip/hip_fp16.h>

#define TSTEPS 1019
#define BATCH 8
#define CIN 4
#define LEN 524288
#define COUT 512
#define HID 512
#define KERN 3072
#define CSTRIDE 512
#define KTOT (CIN * KERN)          // 12288
#define MROWS (TSTEPS * BATCH)     // 8152

typedef _Float16 half2_v __attribute__((ext_vector_type(2)));

#if defined(__has_builtin)
#if __has_builtin(__builtin_amdgcn_fdot2)
#define HAVE_FDOT2 1
#endif
#endif

__device__ __forceinline__ float dot2f(__half2 a, __half2 b, float c) {
#ifdef HAVE_FDOT2
    return __builtin_amdgcn_fdot2(__builtin_bit_cast(half2_v, a),
                                  __builtin_bit_cast(half2_v, b), c, false);
#else
    float2 af = __half22float2(a), bf = __half22float2(b);
    return fmaf(af.y, bf.y, fmaf(af.x, bf.x, c));
#endif
}

// ---------------------------------------------------------------------------
// Conv1d as implicit GEMM: C[m][co] = sum_k A[m][k] * W[co][k] + bias[co]
// m = t*8 + b (t-major so gi/ys layouts fall out directly)
// A[m][k] = input[b][k/3072][t*512 + k%3072]  (k-slice of 16 stays in one ci)
// ---------------------------------------------------------------------------
__global__ __launch_bounds__(256) void conv_gemm_k(
        const float* __restrict__ in, const float* __restrict__ w,
        const float* __restrict__ bias, float* __restrict__ out) {
    // k-major LDS tiles, +4 pad keeps float4 alignment and spreads banks
    __shared__ float As[16][68];
    __shared__ float Bs[16][68];
    const int m0 = blockIdx.y * 64;
    const int n0 = blockIdx.x * 64;
    const int tid = threadIdx.x;
    const int tx = tid & 15, ty = tid >> 4;   // 16x16 threads, 4x4 microtile
    const int lr = tid >> 2;                  // 0..63 load row
    const int lk = (tid & 3) << 2;            // 0,4,8,12 load k-offset

    float acc[4][4] = {};

    int mA = m0 + lr; if (mA > MROWS - 1) mA = MROWS - 1;  // clamp tail rows
    const int tA = mA >> 3, bA = mA & 7;
    const float* inb = in + (size_t)bA * CIN * LEN + (size_t)tA * CSTRIDE;
    const float* wB  = w + (size_t)(n0 + lr) * KTOT;

    for (int k0 = 0; k0 < KTOT; k0 += 16) {
        const int k = k0 + lk;
        const int ci = k / KERN, kr = k - ci * KERN;
        float4 va = *reinterpret_cast<const float4*>(inb + (size_t)ci * LEN + kr);
        float4 vb = *reinterpret_cast<const float4*>(wB + k);
        As[lk + 0][lr] = va.x; As[lk + 1][lr] = va.y;
        As[lk + 2][lr] = va.z; As[lk + 3][lr] = va.w;
        Bs[lk + 0][lr] = vb.x; Bs[lk + 1][lr] = vb.y;
        Bs[lk + 2][lr] = vb.z; Bs[lk + 3][lr] = vb.w;
        __syncthreads();
        #pragma unroll
        for (int kk = 0; kk < 16; ++kk) {
            float a[4], bv[4];
            *reinterpret_cast<float4*>(a)  = *reinterpret_cast<const float4*>(&As[kk][ty * 4]);
            *reinterpret_cast<float4*>(bv) = *reinterpret_cast<const float4*>(&Bs[kk][tx * 4]);
            #pragma unroll
            for (int i = 0; i < 4; ++i)
                #pragma unroll
                for (int j = 0; j < 4; ++j)
                    acc[i][j] = fmaf(a[i], bv[j], acc[i][j]);
        }
        __syncthreads();
    }
    const int n = n0 + tx * 4;
    float4 b4 = *reinterpret_cast<const float4*>(bias + n);
    #pragma unroll
    for (int i = 0; i < 4; ++i) {
        int m = m0 + ty * 4 + i;
        if (m < MROWS) {
            float4 o = make_float4(acc[i][0] + b4.x, acc[i][1] + b4.y,
                                   acc[i][2] + b4.z, acc[i][3] + b4.w);
            *reinterpret_cast<float4*>(out + (size_t)m * COUT + n) = o;
        }
    }
}

// ---------------------------------------------------------------------------
// gi[m][n] = sum_c conv_out[m][c] * w_ih[n][c] + b_ih[n]   (M=8152,N=1536,K=512)
// ---------------------------------------------------------------------------
__global__ __launch_bounds__(256) void proj_gemm_k(
        const float* __restrict__ A, const float* __restrict__ w,
        const float* __restrict__ bias, float* __restrict__ out) {
    __shared__ float As[16][68];
    __shared__ float Bs[16][68];
    const int m0 = blockIdx.y * 64;
    const int n0 = blockIdx.x * 64;
    const int tid = threadIdx.x;
    const int tx = tid & 15, ty = tid >> 4;
    const int lr = tid >> 2;
    const int lk = (tid & 3) << 2;

    float acc[4][4] = {};
    int mA = m0 + lr; if (mA > MROWS - 1) mA = MROWS - 1;
    const float* Ar = A + (size_t)mA * COUT;
    const float* wB = w + (size_t)(n0 + lr) * COUT;

    for (int k0 = 0; k0 < COUT; k0 += 16) {
        float4 va = *reinterpret_cast<const float4*>(Ar + k0 + lk);
        float4 vb = *reinterpret_cast<const float4*>(wB + k0 + lk);
        As[lk + 0][lr] = va.x; As[lk + 1][lr] = va.y;
        As[lk + 2][lr] = va.z; As[lk + 3][lr] = va.w;
        Bs[lk + 0][lr] = vb.x; Bs[lk + 1][lr] = vb.y;
        Bs[lk + 2][lr] = vb.z; Bs[lk + 3][lr] = vb.w;
        __syncthreads();
        #pragma unroll
        for (int kk = 0; kk < 16; ++kk) {
            float a[4], bv[4];
            *reinterpret_cast<float4*>(a)  = *reinterpret_cast<const float4*>(&As[kk][ty * 4]);
            *reinterpret_cast<float4*>(bv) = *reinterpret_cast<const float4*>(&Bs[kk][tx * 4]);
            #pragma unroll
            for (int i = 0; i < 4; ++i)
                #pragma unroll
                for (int j = 0; j < 4; ++j)
                    acc[i][j] = fmaf(a[i], bv[j], acc[i][j]);
        }
        __syncthreads();
    }
    const int n = n0 + tx * 4;
    float4 b4 = *reinterpret_cast<const float4*>(bias + n);
    #pragma unroll
    for (int i = 0; i < 4; ++i) {
        int m = m0 + ty * 4 + i;
        if (m < MROWS) {
            float4 o = make_float4(acc[i][0] + b4.x, acc[i][1] + b4.y,
                                   acc[i][2] + b4.z, acc[i][3] + b4.w);
            *reinterpret_cast<float4*>(out + (size_t)m * 1536 + n) = o;
        }
    }
}

// ---------------------------------------------------------------------------
// GRU scan. 32 blocks = 8 batch-teams x 4 slice-blocks (b = bid%8 so a team
// lands on one XCD under round-robin dispatch; correctness placement-free).
// Block (b,isl) owns h[isl*128 .. +128) and w_hh rows {j, j+512, j+1024},
// held as fp16 in 192 VGPRs/thread (393 KB/CU = 77% of the 512 KB file).
// Per step: dot2 matvec (768 cyc) -> LDS reduce -> gate math -> h-slice
// exchange via double-buffered global h_ex + agent-scope release/acquire flags.
// ---------------------------------------------------------------------------
__global__ __launch_bounds__(512, 2) void gru_scan_k(
        const float* __restrict__ gi, const float* __restrict__ w_hh,
        const float* __restrict__ b_hh, const float* __restrict__ hidden,
        float* __restrict__ out, float* __restrict__ h_ex,
        int* __restrict__ flags) {
    const int bid = blockIdx.x;
    const int b   = bid & 7;
    const int isl = bid >> 3;            // slice 0..3
    const int tid = threadIdx.x;
    const int q   = tid >> 7;            // k-quarter 0..3 (uniform per wave-pair)
    const int g   = tid & 127;           // row-in-slice
    const int j   = isl * 128 + g;

    __shared__ __align__(16) __half hh[512];      // h_t as fp16 for dot2
    __shared__ float p_lds[1920];                  // partials [gate][g][q] stride 5

    // Load this thread's w_hh fragment: 3 gates x 128 k as fp16 (192 VGPRs).
    __half2 wreg[3][64];
    #pragma unroll
    for (int m = 0; m < 3; ++m) {
        const float* wp = w_hh + (size_t)(j + m * 512) * HID + q * 128;
        #pragma unroll
        for (int kk = 0; kk < 32; ++kk) {
            float4 v = reinterpret_cast<const float4*>(wp)[kk];
            wreg[m][2 * kk]     = __halves2half2(__float2half_rn(v.x), __float2half_rn(v.y));
            wreg[m][2 * kk + 1] = __halves2half2(__float2half_rn(v.z), __float2half_rn(v.w));
        }
    }

    float bhr = 0.f, bhz = 0.f, bhn = 0.f, hprev = 0.f;
    if (tid < 128) {
        const int jg = isl * 128 + tid;
        bhr = b_hh[jg]; bhz = b_hh[jg + 512]; bhn = b_hh[jg + 1024];
        hprev = hidden[b * HID + jg];
    }
    hh[tid] = __float2half(hidden[b * HID + tid]);
    __syncthreads();

    for (int t = 0; t < TSTEPS; ++t) {
        // Prefetch gi early; latency hides under the dot phase.
        float gir = 0.f, giz = 0.f, gin = 0.f;
        if (tid < 128) {
            const float* gp = gi + (size_t)(t * BATCH + b) * 1536 + isl * 128 + tid;
            gir = gp[0]; giz = gp[512]; gin = gp[1024];
        }
        // Matvec partials: uniform-address (broadcast) LDS reads of h.
        const __half2* hv = reinterpret_cast<const __half2*>(hh) + q * 64;
        float a0 = 0, a1 = 0, a2 = 0, c0 = 0, c1 = 0, c2 = 0;
        #pragma unroll
        for (int kk = 0; kk < 64; kk += 2) {
            __half2 h2a = hv[kk], h2b = hv[kk + 1];
            a0 = dot2f(wreg[0][kk], h2a, a0);
            a1 = dot2f(wreg[1][kk], h2a, a1);
            a2 = dot2f(wreg[2][kk], h2a, a2);
            c0 = dot2f(wreg[0][kk + 1], h2b, c0);
            c1 = dot2f(wreg[1][kk + 1], h2b, c1);
            c2 = dot2f(wreg[2][kk + 1], h2b, c2);
        }
        p_lds[(0 * 128 + g) * 5 + q] = a0 + c0;   // stride 5: gcd(5,32)=1, no conflicts
        p_lds[(1 * 128 + g) * 5 + q] = a1 + c1;
        p_lds[(2 * 128 + g) * 5 + q] = a2 + c2;
        __syncthreads();

        float hnew = 0.f;
        if (tid < 128) {
            const float* pr = &p_lds[(0 * 128 + tid) * 5];
            const float* pz = &p_lds[(1 * 128 + tid) * 5];
            const float* pn = &p_lds[(2 * 128 + tid) * 5];
            const float ghr = pr[0] + pr[1] + pr[2] + pr[3] + bhr;
            const float ghz = pz[0] + pz[1] + pz[2] + pz[3] + bhz;
            const float ghn = pn[0] + pn[1] + pn[2] + pn[3] + bhn;
            const float r = 1.f / (1.f + __expf(-(gir + ghr)));
            const float z = 1.f / (1.f + __expf(-(giz + ghz)));
            const float nx = gin + r * ghn;
            const float n = 1.f - 2.f / (__expf(2.f * nx) + 1.f);  // tanh
            hnew = (1.f - z) * n + z * hprev;
            hprev = hnew;
            out[(size_t)(t * BATCH + b) * HID + isl * 128 + tid] = hnew;
        }
        if (t == TSTEPS - 1) break;

        // Exchange h slices within the 4-block team (double-buffered by step).
        float* hx = h_ex + (size_t)(((t + 1) & 1) * BATCH + b) * HID;
        if (tid < 128) hx[isl * 128 + tid] = hnew;
        __syncthreads();                       // drains all waves' stores (vmcnt(0) before s_barrier)
        if (tid == 0) {
            __threadfence();
            __hip_atomic_store(&flags[(b * 4 + isl) * 16], t + 1,
                               __ATOMIC_RELEASE, __HIP_MEMORY_SCOPE_AGENT);
        }
        if (tid < 4) {
            while (__hip_atomic_load(&flags[(b * 4 + tid) * 16],
                                     __ATOMIC_ACQUIRE, __HIP_MEMORY_SCOPE_AGENT) < t + 1) {
                __builtin_amdgcn_s_sleep(1);
            }
        }
        __syncthreads();
        hh[tid] = __float2half(hx[tid]);       // full h_{t+1} -> LDS fp16
        __syncthreads();
    }
    if (tid < 128)
        out[(size_t)TSTEPS * BATCH * HID + b * HID + isl * 128 + tid] = hprev;
}

extern "C" void kernel_launch(void* const* d_in, const int* in_sizes, int n_in,
                              void* d_out, int out_size, void* d_ws, size_t ws_size,
                              hipStream_t stream) {
    (void)in_sizes; (void)n_in; (void)out_size; (void)ws_size;
    const float* input  = (const float*)d_in[0];
    const float* hidden = (const float*)d_in[1];
    const float* conv_w = (const float*)d_in[2];
    const float* conv_b = (const float*)d_in[3];
    const float* w_ih   = (const float*)d_in[4];
    const float* w_hh   = (const float*)d_in[5];
    const float* b_ih   = (const float*)d_in[6];
    const float* b_hh   = (const float*)d_in[7];
    float* out = (float*)d_out;

    char* ws = (char*)d_ws;
    float* conv_out = (float*)ws;                                   // 16,695,296 B
    float* gi       = (float*)(ws + 16695296);                      // 50,085,888 B
    float* h_ex     = (float*)(ws + 16695296 + 50085888);           // 32,768 B
    int*   flags    = (int*)  (ws + 16695296 + 50085888 + 32768);   // 2,048 B

    hipMemsetAsync(flags, 0, 2048, stream);   // reset team sync counters each launch

    dim3 cgrid(COUT / 64, (MROWS + 63) / 64);         // 8 x 128
    conv_gemm_k<<<cgrid, 256, 0, stream>>>(input, conv_w, conv_b, conv_out);

    dim3 pgrid(1536 / 64, (MROWS + 63) / 64);         // 24 x 128
    proj_gemm_k<<<pgrid, 256, 0, stream>>>(conv_out, w_ih, b_ih, gi);

    gru_scan_k<<<32, 512, 0, stream>>>(gi, w_hh, b_hh, hidden, out, h_ex, flags);
}

// Round 3
// 3720.399 us; speedup vs baseline: 1.3904x; 1.3904x over previous
//
#include <hip/hip_runtime.h>
#include <hip/hip_fp16.h>

#define TSTEPS 1019
#define BATCH 8
#define CIN 4
#define LEN 524288
#define COUT 512
#define HID 512
#define KERN 3072
#define CSTRIDE 512
#define KTOT (CIN * KERN)          // 12288
#define MROWS (TSTEPS * BATCH)     // 8152

typedef _Float16 half2_v __attribute__((ext_vector_type(2)));

#if defined(__has_builtin)
#if __has_builtin(__builtin_amdgcn_fdot2)
#define HAVE_FDOT2 1
#endif
#endif

__device__ __forceinline__ float dot2f(__half2 a, __half2 b, float c) {
#ifdef HAVE_FDOT2
    return __builtin_amdgcn_fdot2(__builtin_bit_cast(half2_v, a),
                                  __builtin_bit_cast(half2_v, b), c, false);
#else
    float2 af = __half22float2(a), bf = __half22float2(b);
    return fmaf(af.y, bf.y, fmaf(af.x, bf.x, c));
#endif
}

struct __align__(16) H2x4 { __half2 x, y, z, w; };

// ---------------------------------------------------------------------------
// Conv1d as implicit GEMM (unchanged)
// ---------------------------------------------------------------------------
__global__ __launch_bounds__(256) void conv_gemm_k(
        const float* __restrict__ in, const float* __restrict__ w,
        const float* __restrict__ bias, float* __restrict__ out) {
    __shared__ float As[16][68];
    __shared__ float Bs[16][68];
    const int m0 = blockIdx.y * 64;
    const int n0 = blockIdx.x * 64;
    const int tid = threadIdx.x;
    const int tx = tid & 15, ty = tid >> 4;
    const int lr = tid >> 2;
    const int lk = (tid & 3) << 2;

    float acc[4][4] = {};

    int mA = m0 + lr; if (mA > MROWS - 1) mA = MROWS - 1;
    const int tA = mA >> 3, bA = mA & 7;
    const float* inb = in + (size_t)bA * CIN * LEN + (size_t)tA * CSTRIDE;
    const float* wB  = w + (size_t)(n0 + lr) * KTOT;

    for (int k0 = 0; k0 < KTOT; k0 += 16) {
        const int k = k0 + lk;
        const int ci = k / KERN, kr = k - ci * KERN;
        float4 va = *reinterpret_cast<const float4*>(inb + (size_t)ci * LEN + kr);
        float4 vb = *reinterpret_cast<const float4*>(wB + k);
        As[lk + 0][lr] = va.x; As[lk + 1][lr] = va.y;
        As[lk + 2][lr] = va.z; As[lk + 3][lr] = va.w;
        Bs[lk + 0][lr] = vb.x; Bs[lk + 1][lr] = vb.y;
        Bs[lk + 2][lr] = vb.z; Bs[lk + 3][lr] = vb.w;
        __syncthreads();
        #pragma unroll
        for (int kk = 0; kk < 16; ++kk) {
            float a[4], bv[4];
            *reinterpret_cast<float4*>(a)  = *reinterpret_cast<const float4*>(&As[kk][ty * 4]);
            *reinterpret_cast<float4*>(bv) = *reinterpret_cast<const float4*>(&Bs[kk][tx * 4]);
            #pragma unroll
            for (int i = 0; i < 4; ++i)
                #pragma unroll
                for (int j = 0; j < 4; ++j)
                    acc[i][j] = fmaf(a[i], bv[j], acc[i][j]);
        }
        __syncthreads();
    }
    const int n = n0 + tx * 4;
    float4 b4 = *reinterpret_cast<const float4*>(bias + n);
    #pragma unroll
    for (int i = 0; i < 4; ++i) {
        int m = m0 + ty * 4 + i;
        if (m < MROWS) {
            float4 o = make_float4(acc[i][0] + b4.x, acc[i][1] + b4.y,
                                   acc[i][2] + b4.z, acc[i][3] + b4.w);
            *reinterpret_cast<float4*>(out + (size_t)m * COUT + n) = o;
        }
    }
}

// ---------------------------------------------------------------------------
// gi projection GEMM (unchanged)
// ---------------------------------------------------------------------------
__global__ __launch_bounds__(256) void proj_gemm_k(
        const float* __restrict__ A, const float* __restrict__ w,
        const float* __restrict__ bias, float* __restrict__ out) {
    __shared__ float As[16][68];
    __shared__ float Bs[16][68];
    const int m0 = blockIdx.y * 64;
    const int n0 = blockIdx.x * 64;
    const int tid = threadIdx.x;
    const int tx = tid & 15, ty = tid >> 4;
    const int lr = tid >> 2;
    const int lk = (tid & 3) << 2;

    float acc[4][4] = {};
    int mA = m0 + lr; if (mA > MROWS - 1) mA = MROWS - 1;
    const float* Ar = A + (size_t)mA * COUT;
    const float* wB = w + (size_t)(n0 + lr) * COUT;

    for (int k0 = 0; k0 < COUT; k0 += 16) {
        float4 va = *reinterpret_cast<const float4*>(Ar + k0 + lk);
        float4 vb = *reinterpret_cast<const float4*>(wB + k0 + lk);
        As[lk + 0][lr] = va.x; As[lk + 1][lr] = va.y;
        As[lk + 2][lr] = va.z; As[lk + 3][lr] = va.w;
        Bs[lk + 0][lr] = vb.x; Bs[lk + 1][lr] = vb.y;
        Bs[lk + 2][lr] = vb.z; Bs[lk + 3][lr] = vb.w;
        __syncthreads();
        #pragma unroll
        for (int kk = 0; kk < 16; ++kk) {
            float a[4], bv[4];
            *reinterpret_cast<float4*>(a)  = *reinterpret_cast<const float4*>(&As[kk][ty * 4]);
            *reinterpret_cast<float4*>(bv) = *reinterpret_cast<const float4*>(&Bs[kk][tx * 4]);
            #pragma unroll
            for (int i = 0; i < 4; ++i)
                #pragma unroll
                for (int j = 0; j < 4; ++j)
                    acc[i][j] = fmaf(a[i], bv[j], acc[i][j]);
        }
        __syncthreads();
    }
    const int n = n0 + tx * 4;
    float4 b4 = *reinterpret_cast<const float4*>(bias + n);
    #pragma unroll
    for (int i = 0; i < 4; ++i) {
        int m = m0 + ty * 4 + i;
        if (m < MROWS) {
            float4 o = make_float4(acc[i][0] + b4.x, acc[i][1] + b4.y,
                                   acc[i][2] + b4.z, acc[i][3] + b4.w);
            *reinterpret_cast<float4*>(out + (size_t)m * 1536 + n) = o;
        }
    }
}

// ---------------------------------------------------------------------------
// GRU scan, round 3. Exchange words are {epoch:32 | 2x fp16 h:32}, one relaxed
// agent-scope atomic store per pair, per-thread relaxed polls (data-is-flag).
// DOUBLE-BUFFERED by step parity (round 2 single-buffer deadlocked: a fast
// block could overwrite its word with epoch t+2 while a slow peer still
// polled ==t+1). With 2 buffers, a word in buffer p is rewritten (epoch t+3)
// only after the writer polled epoch t+2, which requires every peer to have
// finished its t+1 poll of buffer p. Exact-match poll is thus safe.
// ---------------------------------------------------------------------------
__global__ __launch_bounds__(512, 1) void gru_scan_k(
        const float* __restrict__ gi, const float* __restrict__ w_hh,
        const float* __restrict__ b_hh, const float* __restrict__ hidden,
        float* __restrict__ out, unsigned long long* __restrict__ h_ex) {
    const int bid = blockIdx.x;
    const int b   = bid & 7;
    const int isl = bid >> 3;            // slice 0..3
    const int tid = threadIdx.x;
    const int q   = tid >> 7;            // k-quarter 0..3 (wave-uniform)
    const int g   = tid & 127;           // row-in-slice
    const int j   = isl * 128 + g;       // owned h row

    __shared__ __align__(16) __half2 hh2[256];   // h_t as fp16 pairs
    __shared__ float p_lds[1920];                // partials [gate][g][q] stride 5

    // w_hh fragment: 3 gates x 128 k as fp16 -> 192 VGPRs/thread.
    __half2 wreg[3][64];
    #pragma unroll
    for (int m = 0; m < 3; ++m) {
        const float* wp = w_hh + (size_t)(j + m * 512) * HID + q * 128;
        #pragma unroll
        for (int kk = 0; kk < 32; ++kk) {
            float4 v = reinterpret_cast<const float4*>(wp)[kk];
            wreg[m][2 * kk]     = __halves2half2(__float2half_rn(v.x), __float2half_rn(v.y));
            wreg[m][2 * kk + 1] = __halves2half2(__float2half_rn(v.z), __float2half_rn(v.w));
        }
    }

    float bhr = 0.f, bhz = 0.f, bhn = 0.f, hprev = 0.f;
    if (tid < 128) {
        bhr = b_hh[j]; bhz = b_hh[j + 512]; bhn = b_hh[j + 1024];
        hprev = hidden[b * HID + j];
    }
    if (tid < 256) {
        float h0a = hidden[b * HID + 2 * tid];
        float h0b = hidden[b * HID + 2 * tid + 1];
        hh2[tid] = __halves2half2(__float2half(h0a), __float2half(h0b));
    }
    __syncthreads();

    // gi for t=0 (prefetched; later steps load t+1 during the poll window)
    float gir = 0.f, giz = 0.f, gin = 0.f;
    if (tid < 128) {
        const float* gp = gi + (size_t)b * 1536 + j;
        gir = gp[0]; giz = gp[512]; gin = gp[1024];
    }

    for (int t = 0; t < TSTEPS; ++t) {
        // --- matvec partials: b128 broadcast reads of h, 192 v_dot2 ---
        const H2x4* hv4 = reinterpret_cast<const H2x4*>(hh2 + q * 64);
        float a0 = 0, a1 = 0, a2 = 0, c0 = 0, c1 = 0, c2 = 0;
        #pragma unroll
        for (int kk = 0; kk < 16; ++kk) {
            H2x4 h4 = hv4[kk];
            a0 = dot2f(wreg[0][4 * kk + 0], h4.x, a0);
            a1 = dot2f(wreg[1][4 * kk + 0], h4.x, a1);
            a2 = dot2f(wreg[2][4 * kk + 0], h4.x, a2);
            c0 = dot2f(wreg[0][4 * kk + 1], h4.y, c0);
            c1 = dot2f(wreg[1][4 * kk + 1], h4.y, c1);
            c2 = dot2f(wreg[2][4 * kk + 1], h4.y, c2);
            a0 = dot2f(wreg[0][4 * kk + 2], h4.z, a0);
            a1 = dot2f(wreg[1][4 * kk + 2], h4.z, a1);
            a2 = dot2f(wreg[2][4 * kk + 2], h4.z, a2);
            c0 = dot2f(wreg[0][4 * kk + 3], h4.w, c0);
            c1 = dot2f(wreg[1][4 * kk + 3], h4.w, c1);
            c2 = dot2f(wreg[2][4 * kk + 3], h4.w, c2);
        }
        p_lds[(0 * 128 + g) * 5 + q] = a0 + c0;   // stride 5: gcd(5,32)=1
        p_lds[(1 * 128 + g) * 5 + q] = a1 + c1;
        p_lds[(2 * 128 + g) * 5 + q] = a2 + c2;
        __syncthreads();   // B1

        // double-buffered exchange region for epoch t+1
        unsigned long long* hx =
            (unsigned long long*)0 /*set below*/;
        hx = /* buffer parity (t+1)&1, batch b */
             /* 2048 words per buffer: 8 batches x 256 */
             (unsigned long long*)((char*)0) ;   // placeholder removed below
        (void)hx;

        float hnew = 0.f;
        if (tid < 128) {
            const float* pr = &p_lds[(0 * 128 + tid) * 5];
            const float* pz = &p_lds[(1 * 128 + tid) * 5];
            const float* pn = &p_lds[(2 * 128 + tid) * 5];
            const float ghr = pr[0] + pr[1] + pr[2] + pr[3] + bhr;
            const float ghz = pz[0] + pz[1] + pz[2] + pz[3] + bhz;
            const float ghn = pn[0] + pn[1] + pn[2] + pn[3] + bhn;
            const float r = 1.f / (1.f + __expf(-(gir + ghr)));
            const float z = 1.f / (1.f + __expf(-(giz + ghz)));
            const float nx = gin + r * ghn;
            const float n = 1.f - 2.f / (__expf(2.f * nx) + 1.f);  // tanh
            hnew = (1.f - z) * n + z * hprev;
            hprev = hnew;
            out[(size_t)(t * BATCH + b) * HID + j] = hnew;
            // publish: pack pair + epoch, one relaxed agent store per pair
            float hother = __shfl_xor(hnew, 1);
            if (!(tid & 1) && t < TSTEPS - 1) {
                unsigned long long* pub = h_ex
                    + (size_t)(((t + 1) & 1) * BATCH + b) * 256
                    + isl * 64 + (tid >> 1);
                __half2 h2 = __halves2half2(__float2half(hnew), __float2half(hother));
                unsigned long long v =
                    ((unsigned long long)(unsigned)(t + 1) << 32) |
                    (unsigned long long)__builtin_bit_cast(unsigned, h2);
                __hip_atomic_store(pub, v, __ATOMIC_RELAXED,
                                   __HIP_MEMORY_SCOPE_AGENT);
            }
        }
        if (t == TSTEPS - 1) break;

        // prefetch gi for t+1 (latency hides under the poll + next matvec)
        if (tid < 128) {
            const float* gp = gi + (size_t)((t + 1) * BATCH + b) * 1536 + j;
            gir = gp[0]; giz = gp[512]; gin = gp[1024];
        }

        // poll exactly the word this thread needs; data carries the epoch
        if (tid < 256) {
            unsigned long long* src = h_ex
                + (size_t)(((t + 1) & 1) * BATCH + b) * 256 + tid;
            unsigned long long v;
            do {
                v = __hip_atomic_load(src, __ATOMIC_RELAXED,
                                      __HIP_MEMORY_SCOPE_AGENT);
            } while ((unsigned)(v >> 32) != (unsigned)(t + 1));
            hh2[tid] = __builtin_bit_cast(__half2, (unsigned)(v & 0xffffffffu));
        }
        __syncthreads();   // B2
    }
    if (tid < 128)
        out[(size_t)TSTEPS * BATCH * HID + b * HID + j] = hprev;
}

extern "C" void kernel_launch(void* const* d_in, const int* in_sizes, int n_in,
                              void* d_out, int out_size, void* d_ws, size_t ws_size,
                              hipStream_t stream) {
    (void)in_sizes; (void)n_in; (void)out_size; (void)ws_size;
    const float* input  = (const float*)d_in[0];
    const float* hidden = (const float*)d_in[1];
    const float* conv_w = (const float*)d_in[2];
    const float* conv_b = (const float*)d_in[3];
    const float* w_ih   = (const float*)d_in[4];
    const float* w_hh   = (const float*)d_in[5];
    const float* b_ih   = (const float*)d_in[6];
    const float* b_hh   = (const float*)d_in[7];
    float* out = (float*)d_out;

    char* ws = (char*)d_ws;
    float* conv_out = (float*)ws;                                   // 16,695,296 B
    float* gi       = (float*)(ws + 16695296);                      // 50,085,888 B
    unsigned long long* h_ex = (unsigned long long*)(ws + 16695296 + 50085888); // 32,768 B

    // reset exchange epochs each launch (replays don't re-poison d_ws)
    hipMemsetAsync(h_ex, 0, 32768, stream);

    dim3 cgrid(COUT / 64, (MROWS + 63) / 64);         // 8 x 128
    conv_gemm_k<<<cgrid, 256, 0, stream>>>(input, conv_w, conv_b, conv_out);

    dim3 pgrid(1536 / 64, (MROWS + 63) / 64);         // 24 x 128
    proj_gemm_k<<<pgrid, 256, 0, stream>>>(conv_out, w_ih, b_ih, gi);

    gru_scan_k<<<32, 512, 0, stream>>>(gi, w_hh, b_hh, hidden, out, h_ex);
}

// Round 4
// 2208.473 us; speedup vs baseline: 2.3423x; 1.6846x over previous
//
#include <hip/hip_runtime.h>
#include <hip/hip_fp16.h>
#include <hip/hip_bf16.h>

#define TSTEPS 1019
#define BATCH 8
#define CIN 4
#define LEN 524288
#define COUT 512
#define HID 512
#define KERN 3072
#define CSTRIDE 512
#define KTOT (CIN * KERN)          // 12288
#define MROWS (TSTEPS * BATCH)     // 8152

typedef _Float16 half2_v __attribute__((ext_vector_type(2)));
typedef __attribute__((ext_vector_type(8))) short bf16x8;
typedef __attribute__((ext_vector_type(4))) float f32x4;

#if defined(__has_builtin)
#if __has_builtin(__builtin_amdgcn_fdot2)
#define HAVE_FDOT2 1
#endif
#endif

__device__ __forceinline__ float dot2f(__half2 a, __half2 b, float c) {
#ifdef HAVE_FDOT2
    return __builtin_amdgcn_fdot2(__builtin_bit_cast(half2_v, a),
                                  __builtin_bit_cast(half2_v, b), c, false);
#else
    float2 af = __half22float2(a), bf = __half22float2(b);
    return fmaf(af.y, bf.y, fmaf(af.x, bf.x, c));
#endif
}

struct __align__(16) H2x4 { __half2 x, y, z, w; };

__device__ __forceinline__ short bfc(float x) {
    return (short)__builtin_bit_cast(unsigned short, __float2bfloat16(x));
}

__device__ __forceinline__ void load_lds16(const unsigned short* g, unsigned short* l) {
    __builtin_amdgcn_global_load_lds(
        (const __attribute__((address_space(1))) void*)g,
        (__attribute__((address_space(3))) void*)l, 16, 0, 0);
}

// ---------------------------------------------------------------------------
// fp32 -> bf16 convert (vectorized, grid-stride)
// ---------------------------------------------------------------------------
__global__ __launch_bounds__(256) void f2bf_k(
        const float* __restrict__ a, unsigned short* __restrict__ o, int n4) {
    int i = blockIdx.x * blockDim.x + threadIdx.x;
    int stride = gridDim.x * blockDim.x;
    for (; i < n4; i += stride) {
        float4 f = reinterpret_cast<const float4*>(a)[i];
        ushort4 u;
        u.x = (unsigned short)bfc(f.x); u.y = (unsigned short)bfc(f.y);
        u.z = (unsigned short)bfc(f.z); u.w = (unsigned short)bfc(f.w);
        reinterpret_cast<ushort4*>(o)[i] = u;
    }
}

// ---------------------------------------------------------------------------
// Conv1d as implicit GEMM on MFMA. C[m][n] = sum_k A[m][k] * W[n][k] + b[n]
// m = t*8+b, k = ci*3072+kr; A read from fp32 input (reg-staged, cvt, swizzled
// ds_write); B from pre-converted bf16 weights via global_load_lds with
// pre-swizzled source (chunk c = slot ^ (row&7)). 128x128 tile, BK=64,
// 4 waves 2x2, double-buffered LDS, one barrier per K-tile.
// ---------------------------------------------------------------------------
__global__ __launch_bounds__(256, 2) void conv_mfma_k(
        const float* __restrict__ in, const unsigned short* __restrict__ wb,
        const float* __restrict__ bias, unsigned short* __restrict__ out) {
    __shared__ unsigned short At[2][128 * 64];   // 16 KB each buf
    __shared__ unsigned short Bt[2][128 * 64];
    const int m0 = blockIdx.y * 128;
    const int n0 = blockIdx.x * 128;
    const int tid = threadIdx.x;
    const int w = tid >> 6, l = tid & 63;
    const int wm = w >> 1, wn = w & 1;           // wave 2x2 over (M,N)
    const int fr = l & 15, fq = l >> 4;          // frag 16-index, k-quad

    // A staging: thread -> row ra (0..127), half hh (0/1 -> 32 elems)
    const int ra = tid >> 1, hh = tid & 1;
    int mA = m0 + ra; if (mA > MROWS - 1) mA = MROWS - 1;
    const int tA = mA >> 3, bA = mA & 7;

    f32x4 acc[4][4] = {};

    const int NT = KTOT / 64;   // 192 K-tiles

    // ---- prologue: stage tile 0 into buf 0 ----
    {
        const int k0 = 0, ci = 0, kr = 0;
        const float* src = in + (size_t)(bA * CIN + ci) * LEN
                              + (size_t)tA * CSTRIDE + kr + hh * 32;
        #pragma unroll
        for (int cc = 0; cc < 4; ++cc) {
            float4 f0 = reinterpret_cast<const float4*>(src)[cc * 2];
            float4 f1 = reinterpret_cast<const float4*>(src)[cc * 2 + 1];
            bf16x8 v;
            v[0] = bfc(f0.x); v[1] = bfc(f0.y); v[2] = bfc(f0.z); v[3] = bfc(f0.w);
            v[4] = bfc(f1.x); v[5] = bfc(f1.y); v[6] = bfc(f1.z); v[7] = bfc(f1.w);
            const int c = hh * 4 + cc, s = c ^ (ra & 7);
            *reinterpret_cast<bf16x8*>(&At[0][ra * 64 + s * 8]) = v;
        }
        #pragma unroll
        for (int i = 0; i < 4; ++i) {
            const int rb = w * 32 + i * 8 + (l >> 3);
            const int s = l & 7, c = s ^ (rb & 7);
            load_lds16(wb + (size_t)(n0 + rb) * KTOT + k0 + c * 8,
                       &Bt[0][(w * 32 + i * 8) * 64]);
        }
    }
    __syncthreads();

    int cur = 0;
    for (int t = 0; t < NT; ++t) {
        const int nxt = cur ^ 1;
        float4 fA[8];
        const bool more = (t + 1 < NT);
        if (more) {
            const int k0 = (t + 1) * 64;
            const int ci = k0 / KERN, kr = k0 - ci * KERN;
            const float* src = in + (size_t)(bA * CIN + ci) * LEN
                                  + (size_t)tA * CSTRIDE + kr + hh * 32;
            #pragma unroll
            for (int v = 0; v < 8; ++v)
                fA[v] = reinterpret_cast<const float4*>(src)[v];
            #pragma unroll
            for (int i = 0; i < 4; ++i) {
                const int rb = w * 32 + i * 8 + (l >> 3);
                const int s = l & 7, c = s ^ (rb & 7);
                load_lds16(wb + (size_t)(n0 + rb) * KTOT + k0 + c * 8,
                           &Bt[nxt][(w * 32 + i * 8) * 64]);
            }
        }
        // ---- MFMA on cur ----
        #pragma unroll
        for (int ks = 0; ks < 2; ++ks) {
            bf16x8 af[4], bfg[4];
            #pragma unroll
            for (int mf = 0; mf < 4; ++mf) {
                const int rA = wm * 64 + mf * 16 + fr;
                const int cw = ks * 4 + fq, s = cw ^ (rA & 7);
                af[mf] = *reinterpret_cast<const bf16x8*>(&At[cur][rA * 64 + s * 8]);
            }
            #pragma unroll
            for (int nf = 0; nf < 4; ++nf) {
                const int rB = wn * 64 + nf * 16 + fr;
                const int cw = ks * 4 + fq, s = cw ^ (rB & 7);
                bfg[nf] = *reinterpret_cast<const bf16x8*>(&Bt[cur][rB * 64 + s * 8]);
            }
            #pragma unroll
            for (int mf = 0; mf < 4; ++mf)
                #pragma unroll
                for (int nf = 0; nf < 4; ++nf)
                    acc[mf][nf] = __builtin_amdgcn_mfma_f32_16x16x32_bf16(
                        af[mf], bfg[nf], acc[mf][nf], 0, 0, 0);
        }
        // ---- finish A stage (cvt + swizzled ds_write) ----
        if (more) {
            #pragma unroll
            for (int cc = 0; cc < 4; ++cc) {
                float4 f0 = fA[cc * 2], f1 = fA[cc * 2 + 1];
                bf16x8 v;
                v[0] = bfc(f0.x); v[1] = bfc(f0.y); v[2] = bfc(f0.z); v[3] = bfc(f0.w);
                v[4] = bfc(f1.x); v[5] = bfc(f1.y); v[6] = bfc(f1.z); v[7] = bfc(f1.w);
                const int c = hh * 4 + cc, s = c ^ (ra & 7);
                *reinterpret_cast<bf16x8*>(&At[nxt][ra * 64 + s * 8]) = v;
            }
        }
        __syncthreads();
        cur = nxt;
    }

    // ---- epilogue: C = acc + bias -> bf16 ----
    #pragma unroll
    for (int nf = 0; nf < 4; ++nf) {
        const int n = n0 + wn * 64 + nf * 16 + fr;
        const float bv = bias[n];
        #pragma unroll
        for (int mf = 0; mf < 4; ++mf) {
            #pragma unroll
            for (int i = 0; i < 4; ++i) {
                const int m = m0 + wm * 64 + mf * 16 + fq * 4 + i;
                if (m < MROWS)
                    out[(size_t)m * COUT + n] =
                        (unsigned short)bfc(acc[mf][nf][i] + bv);
            }
        }
    }
}

// ---------------------------------------------------------------------------
// gi = conv_out(bf16) . w_ih^T + b_ih   (M=8152, N=1536, K=512), fp32 out.
// Both operands staged via global_load_lds with pre-swizzled source.
// ---------------------------------------------------------------------------
__global__ __launch_bounds__(256, 2) void proj_mfma_k(
        const unsigned short* __restrict__ A, const unsigned short* __restrict__ wb,
        const float* __restrict__ bias, float* __restrict__ out) {
    __shared__ unsigned short At[2][128 * 64];
    __shared__ unsigned short Bt[2][128 * 64];
    const int m0 = blockIdx.y * 128;
    const int n0 = blockIdx.x * 128;
    const int tid = threadIdx.x;
    const int w = tid >> 6, l = tid & 63;
    const int wm = w >> 1, wn = w & 1;
    const int fr = l & 15, fq = l >> 4;

    f32x4 acc[4][4] = {};
    const int NT = COUT / 64;   // 8 K-tiles

    auto stage = [&](int buf, int k0) {
        #pragma unroll
        for (int i = 0; i < 4; ++i) {
            const int r = w * 32 + i * 8 + (l >> 3);
            const int s = l & 7, c = s ^ (r & 7);
            int mA = m0 + r; if (mA > MROWS - 1) mA = MROWS - 1;
            load_lds16(A + (size_t)mA * COUT + k0 + c * 8,
                       &At[buf][(w * 32 + i * 8) * 64]);
            load_lds16(wb + (size_t)(n0 + r) * COUT + k0 + c * 8,
                       &Bt[buf][(w * 32 + i * 8) * 64]);
        }
    };

    stage(0, 0);
    __syncthreads();
    int cur = 0;
    for (int t = 0; t < NT; ++t) {
        const int nxt = cur ^ 1;
        if (t + 1 < NT) stage(nxt, (t + 1) * 64);
        #pragma unroll
        for (int ks = 0; ks < 2; ++ks) {
            bf16x8 af[4], bfg[4];
            #pragma unroll
            for (int mf = 0; mf < 4; ++mf) {
                const int rA = wm * 64 + mf * 16 + fr;
                const int cw = ks * 4 + fq, s = cw ^ (rA & 7);
                af[mf] = *reinterpret_cast<const bf16x8*>(&At[cur][rA * 64 + s * 8]);
            }
            #pragma unroll
            for (int nf = 0; nf < 4; ++nf) {
                const int rB = wn * 64 + nf * 16 + fr;
                const int cw = ks * 4 + fq, s = cw ^ (rB & 7);
                bfg[nf] = *reinterpret_cast<const bf16x8*>(&Bt[cur][rB * 64 + s * 8]);
            }
            #pragma unroll
            for (int mf = 0; mf < 4; ++mf)
                #pragma unroll
                for (int nf = 0; nf < 4; ++nf)
                    acc[mf][nf] = __builtin_amdgcn_mfma_f32_16x16x32_bf16(
                        af[mf], bfg[nf], acc[mf][nf], 0, 0, 0);
        }
        __syncthreads();
        cur = nxt;
    }

    #pragma unroll
    for (int nf = 0; nf < 4; ++nf) {
        const int n = n0 + wn * 64 + nf * 16 + fr;
        const float bv = bias[n];
        #pragma unroll
        for (int mf = 0; mf < 4; ++mf) {
            #pragma unroll
            for (int i = 0; i < 4; ++i) {
                const int m = m0 + wm * 64 + mf * 16 + fq * 4 + i;
                if (m < MROWS)
                    out[(size_t)m * 1536 + n] = acc[mf][nf][i] + bv;
            }
        }
    }
}

// ---------------------------------------------------------------------------
// GRU scan (unchanged from round 3 — proven). Packed {epoch:32|2xfp16:32}
// words, relaxed agent-scope store/poll, double-buffered by step parity.
// ---------------------------------------------------------------------------
__global__ __launch_bounds__(512, 1) void gru_scan_k(
        const float* __restrict__ gi, const float* __restrict__ w_hh,
        const float* __restrict__ b_hh, const float* __restrict__ hidden,
        float* __restrict__ out, unsigned long long* __restrict__ h_ex) {
    const int bid = blockIdx.x;
    const int b   = bid & 7;
    const int isl = bid >> 3;
    const int tid = threadIdx.x;
    const int q   = tid >> 7;
    const int g   = tid & 127;
    const int j   = isl * 128 + g;

    __shared__ __align__(16) __half2 hh2[256];
    __shared__ float p_lds[1920];

    __half2 wreg[3][64];
    #pragma unroll
    for (int m = 0; m < 3; ++m) {
        const float* wp = w_hh + (size_t)(j + m * 512) * HID + q * 128;
        #pragma unroll
        for (int kk = 0; kk < 32; ++kk) {
            float4 v = reinterpret_cast<const float4*>(wp)[kk];
            wreg[m][2 * kk]     = __halves2half2(__float2half_rn(v.x), __float2half_rn(v.y));
            wreg[m][2 * kk + 1] = __halves2half2(__float2half_rn(v.z), __float2half_rn(v.w));
        }
    }

    float bhr = 0.f, bhz = 0.f, bhn = 0.f, hprev = 0.f;
    if (tid < 128) {
        bhr = b_hh[j]; bhz = b_hh[j + 512]; bhn = b_hh[j + 1024];
        hprev = hidden[b * HID + j];
    }
    if (tid < 256) {
        float h0a = hidden[b * HID + 2 * tid];
        float h0b = hidden[b * HID + 2 * tid + 1];
        hh2[tid] = __halves2half2(__float2half(h0a), __float2half(h0b));
    }
    __syncthreads();

    float gir = 0.f, giz = 0.f, gin = 0.f;
    if (tid < 128) {
        const float* gp = gi + (size_t)b * 1536 + j;
        gir = gp[0]; giz = gp[512]; gin = gp[1024];
    }

    for (int t = 0; t < TSTEPS; ++t) {
        const H2x4* hv4 = reinterpret_cast<const H2x4*>(hh2 + q * 64);
        float a0 = 0, a1 = 0, a2 = 0, c0 = 0, c1 = 0, c2 = 0;
        #pragma unroll
        for (int kk = 0; kk < 16; ++kk) {
            H2x4 h4 = hv4[kk];
            a0 = dot2f(wreg[0][4 * kk + 0], h4.x, a0);
            a1 = dot2f(wreg[1][4 * kk + 0], h4.x, a1);
            a2 = dot2f(wreg[2][4 * kk + 0], h4.x, a2);
            c0 = dot2f(wreg[0][4 * kk + 1], h4.y, c0);
            c1 = dot2f(wreg[1][4 * kk + 1], h4.y, c1);
            c2 = dot2f(wreg[2][4 * kk + 1], h4.y, c2);
            a0 = dot2f(wreg[0][4 * kk + 2], h4.z, a0);
            a1 = dot2f(wreg[1][4 * kk + 2], h4.z, a1);
            a2 = dot2f(wreg[2][4 * kk + 2], h4.z, a2);
            c0 = dot2f(wreg[0][4 * kk + 3], h4.w, c0);
            c1 = dot2f(wreg[1][4 * kk + 3], h4.w, c1);
            c2 = dot2f(wreg[2][4 * kk + 3], h4.w, c2);
        }
        p_lds[(0 * 128 + g) * 5 + q] = a0 + c0;
        p_lds[(1 * 128 + g) * 5 + q] = a1 + c1;
        p_lds[(2 * 128 + g) * 5 + q] = a2 + c2;
        __syncthreads();   // B1

        float hnew = 0.f;
        if (tid < 128) {
            const float* pr = &p_lds[(0 * 128 + tid) * 5];
            const float* pz = &p_lds[(1 * 128 + tid) * 5];
            const float* pn = &p_lds[(2 * 128 + tid) * 5];
            const float ghr = pr[0] + pr[1] + pr[2] + pr[3] + bhr;
            const float ghz = pz[0] + pz[1] + pz[2] + pz[3] + bhz;
            const float ghn = pn[0] + pn[1] + pn[2] + pn[3] + bhn;
            const float r = 1.f / (1.f + __expf(-(gir + ghr)));
            const float z = 1.f / (1.f + __expf(-(giz + ghz)));
            const float nx = gin + r * ghn;
            const float n = 1.f - 2.f / (__expf(2.f * nx) + 1.f);
            hnew = (1.f - z) * n + z * hprev;
            hprev = hnew;
            out[(size_t)(t * BATCH + b) * HID + j] = hnew;
            float hother = __shfl_xor(hnew, 1);
            if (!(tid & 1) && t < TSTEPS - 1) {
                unsigned long long* pub = h_ex
                    + (size_t)(((t + 1) & 1) * BATCH + b) * 256
                    + isl * 64 + (tid >> 1);
                __half2 h2 = __halves2half2(__float2half(hnew), __float2half(hother));
                unsigned long long v =
                    ((unsigned long long)(unsigned)(t + 1) << 32) |
                    (unsigned long long)__builtin_bit_cast(unsigned, h2);
                __hip_atomic_store(pub, v, __ATOMIC_RELAXED,
                                   __HIP_MEMORY_SCOPE_AGENT);
            }
        }
        if (t == TSTEPS - 1) break;

        if (tid < 128) {
            const float* gp = gi + (size_t)((t + 1) * BATCH + b) * 1536 + j;
            gir = gp[0]; giz = gp[512]; gin = gp[1024];
        }

        if (tid < 256) {
            unsigned long long* src = h_ex
                + (size_t)(((t + 1) & 1) * BATCH + b) * 256 + tid;
            unsigned long long v;
            do {
                v = __hip_atomic_load(src, __ATOMIC_RELAXED,
                                      __HIP_MEMORY_SCOPE_AGENT);
            } while ((unsigned)(v >> 32) != (unsigned)(t + 1));
            hh2[tid] = __builtin_bit_cast(__half2, (unsigned)(v & 0xffffffffu));
        }
        __syncthreads();   // B2
    }
    if (tid < 128)
        out[(size_t)TSTEPS * BATCH * HID + b * HID + j] = hprev;
}

extern "C" void kernel_launch(void* const* d_in, const int* in_sizes, int n_in,
                              void* d_out, int out_size, void* d_ws, size_t ws_size,
                              hipStream_t stream) {
    (void)in_sizes; (void)n_in; (void)out_size; (void)ws_size;
    const float* input  = (const float*)d_in[0];
    const float* hidden = (const float*)d_in[1];
    const float* conv_w = (const float*)d_in[2];
    const float* conv_b = (const float*)d_in[3];
    const float* w_ih   = (const float*)d_in[4];
    const float* w_hh   = (const float*)d_in[5];
    const float* b_ih   = (const float*)d_in[6];
    const float* b_hh   = (const float*)d_in[7];
    float* out = (float*)d_out;

    char* ws = (char*)d_ws;
    float*          gi       = (float*)ws;                          // 50,085,888 B
    unsigned short* conv_out = (unsigned short*)(ws + 50085888);    //  8,347,648 B
    unsigned short* w_bf     = (unsigned short*)(ws + 58433536);    // 12,582,912 B
    unsigned short* wih_bf   = (unsigned short*)(ws + 71016448);    //  1,572,864 B
    unsigned long long* h_ex = (unsigned long long*)(ws + 72589312);//     32,768 B

    // weight converts (bf16)
    f2bf_k<<<2048, 256, 0, stream>>>(conv_w, w_bf, KTOT * COUT / 4);
    f2bf_k<<<768, 256, 0, stream>>>(w_ih, wih_bf, 1536 * COUT / 4);

    // conv stem on MFMA
    dim3 cgrid(4, 64);   // N/128 x ceil(M/128)
    conv_mfma_k<<<cgrid, 256, 0, stream>>>(input, w_bf, conv_b, conv_out);

    // gi projection on MFMA
    dim3 pgrid(12, 64);
    proj_mfma_k<<<pgrid, 256, 0, stream>>>(conv_out, wih_bf, b_ih, gi);

    // reset exchange epochs each launch (replays don't re-poison d_ws)
    hipMemsetAsync(h_ex, 0, 32768, stream);

    gru_scan_k<<<32, 512, 0, stream>>>(gi, w_hh, b_hh, hidden, out, h_ex);
}